// Round 9
// baseline (90.300 us; speedup 1.0000x reference)
//
#include <hip/hip_runtime.h>
#include <hip/hip_bf16.h>
#include <stdint.h>

// ============ R9: DIAGNOSTIC BUILD ============
// Identical to R7 (best: 48.0us) except gemm runs the K-loop NPASS=3 times
// (acc scaled by 1/3 in epilogue; fp32-exact). Purpose: push gemm above the
// ~75us harness fills so rocprof top-5 exposes its counters, and measure
// steady-state per-pass cost = (T_3x - T_1x)/2.

#define NB   16
#define CIN  2048
#define OUTC 256
#define HW   1024
#define BJ   64
#define BK   64
#define NJT  (HW / BJ)          // 16 j-tiles
#define KSTEPS (CIN / BK)       // 32 steps of 64 k
#define NPASS 3                 // diagnostic K-loop repeat

typedef __attribute__((ext_vector_type(8))) short bf16x8;
typedef __attribute__((ext_vector_type(4))) float f32x4;
typedef __attribute__((ext_vector_type(4))) unsigned int u32x4;

__device__ __forceinline__ unsigned int f2bf(float f) {
    union { float f; unsigned int u; } a; a.f = f;
    return (a.u + 0x7FFFu + ((a.u >> 16) & 1u)) >> 16;  // RNE
}

// Raw barrier: drains LDS ops only; global prefetch loads stay in flight.
__device__ __forceinline__ void block_sync_lds() {
    asm volatile("s_waitcnt lgkmcnt(0)" ::: "memory");
    __builtin_amdgcn_s_barrier();
    asm volatile("" ::: "memory");
}

// ---- kernel 1: W fp32 -> bf16 A-fragments in MFMA lane order. ----
__global__ void wprep_kernel(const float* __restrict__ W, unsigned short* __restrict__ Afrag) {
    int g  = blockIdx.x * blockDim.x + threadIdx.x;   // 65536
    int o  = g >> 8;           // 0..255
    int kc = g & 255;          // 8-k chunk within row
    const float4* p = reinterpret_cast<const float4*>(W + o * CIN + kc * 8);
    float4 v0 = p[0], v1 = p[1];
    u32x4 pk;
    pk.x = f2bf(v0.x) | (f2bf(v0.y) << 16);
    pk.y = f2bf(v0.z) | (f2bf(v0.w) << 16);
    pk.z = f2bf(v1.x) | (f2bf(v1.y) << 16);
    pk.w = f2bf(v1.z) | (f2bf(v1.w) << 16);
    int ks32 = kc >> 2, g8 = kc & 3;
    int lane = g8 * 16 + (o & 15), ot = o >> 4;
    *reinterpret_cast<u32x4*>(Afrag + (((size_t)ks32 * 16 + ot) * 64 + lane) * 8) = pk;
}

// ---- kernel 2: R7 GEMM x NPASS. ----
__global__ __launch_bounds__(512, 2) void gemm_stats_kernel(
    const float* __restrict__ x,             // [16][2048][1024]
    const unsigned short* __restrict__ Afrag,
    float* __restrict__ s1_part,             // [NJT][NB][OUTC]
    float* __restrict__ s2_part)             // [256][OUTC]
{
    __shared__ __align__(16) unsigned short B0[4096], B1[4096]; // 8 KB each (64j x 64k)

    const int tid  = threadIdx.x;
    const int lane = tid & 63;
    const int wave = tid >> 6;
    const int blk  = blockIdx.x;   // 0..255
    const int n    = blk >> 4;
    const int jt   = blk & 15;
    const int j0   = jt * BJ;

    const float* xn = x + (size_t)n * CIN * HW;

    const int bj = tid & 63;
    const int kh = tid >> 6;
    const float* Bgp = xn + (size_t)(kh * 8) * HW + j0 + bj;
    const int offB = (kh >> 2) * 2048 + (bj >> 4) * 512 + (kh & 3) * 128 + (bj & 15) * 8;

    // fragment read base (shorts): lane-linear within each (h, ni) 1 KB region
    const int rbase = lane * 8;                    // + h*2048 + ni*512

    // A fragment source: wave-uniform frag base + lane*16B
    const unsigned short* Ab = Afrag + (size_t)lane * 8;

#define LDA(ks, R) { _Pragma("unroll") \
    for (int h = 0; h < 2; ++h) _Pragma("unroll") for (int t = 0; t < 2; ++t) \
        R[h * 2 + t] = *(const u32x4*)(Ab + ((((ks) * 2 + h) * 16 + 2 * wave + t) * 64) * 8); }
#define LDB(ks, F) { const float* p = Bgp + (size_t)(ks) * BK * HW; \
    _Pragma("unroll") for (int i = 0; i < 8; ++i) F[i] = p[(size_t)i * HW]; }
#define WRITEB(Bb, F) { u32x4 pk; \
    pk.x = f2bf(F[0]) | (f2bf(F[1]) << 16); pk.y = f2bf(F[2]) | (f2bf(F[3]) << 16); \
    pk.z = f2bf(F[4]) | (f2bf(F[5]) << 16); pk.w = f2bf(F[6]) | (f2bf(F[7]) << 16); \
    *(u32x4*)&Bb[offB] = pk; }
#define COMPUTE(Bb, R) { _Pragma("unroll") \
    for (int h = 0; h < 2; ++h) { \
        bf16x8 af0 = *(const bf16x8*)&R[h * 2 + 0]; \
        bf16x8 af1 = *(const bf16x8*)&R[h * 2 + 1]; \
        _Pragma("unroll") \
        for (int ni = 0; ni < 4; ++ni) { \
            bf16x8 bf = *(const bf16x8*)&Bb[h * 2048 + ni * 512 + rbase]; \
            acc[0][ni] = __builtin_amdgcn_mfma_f32_16x16x32_bf16(af0, bf, acc[0][ni], 0, 0, 0); \
            acc[1][ni] = __builtin_amdgcn_mfma_f32_16x16x32_bf16(af1, bf, acc[1][ni], 0, 0, 0); \
    } } }

    f32x4 acc[2][4] = {};
    u32x4 Aa0[4], Aa1[4];      // A reg sets: Aa0 <-> even steps (B0), Aa1 <-> odd (B1)
    float Bs0[8], Bs1[8];

    #pragma unroll 1
    for (int pass = 0; pass < NPASS; ++pass) {
        // prologue (per pass): A for steps 0,1; B for 0,1; write B0; reload Bs0 <- 2
        LDA(0, Aa0); LDB(0, Bs0);
        LDA(1, Aa1); LDB(1, Bs1);
        WRITEB(B0, Bs0);
        LDB(2, Bs0);
        block_sync_lds();

        #pragma unroll 1
        for (int ks = 0; ks < KSTEPS; ks += 2) {
            // ---- step ks (even): compute buf0 / Aa0
            COMPUTE(B0, Aa0);
            {
                int ka = (ks + 2 < KSTEPS) ? ks + 2 : KSTEPS - 1;
                LDA(ka, Aa0);
                WRITEB(B1, Bs1);               // stage data ks+1
                int kb = (ks + 3 < KSTEPS) ? ks + 3 : KSTEPS - 1;
                LDB(kb, Bs1);
                block_sync_lds();
            }
            // ---- step ks+1 (odd): compute buf1 / Aa1
            COMPUTE(B1, Aa1);
            {
                int ka = (ks + 3 < KSTEPS) ? ks + 3 : KSTEPS - 1;
                LDA(ka, Aa1);
            }
            if (ks + 2 < KSTEPS) {
                WRITEB(B0, Bs0);               // stage data ks+2
                int kb = (ks + 4 < KSTEPS) ? ks + 4 : KSTEPS - 1;
                LDB(kb, Bs0);
                block_sync_lds();
            }
        }
    }

    // ---- epilogue: scale acc by 1/NPASS, then per-channel sum / sum-sq ----
    // C/D layout: col(j) = lane&15, row = (lane>>4)*4 + r  [m89]
    const float inv_pass = 1.0f / (float)NPASS;
    float rs[2][4], rq[2][4];
    #pragma unroll
    for (int mi = 0; mi < 2; ++mi) {
        #pragma unroll
        for (int r = 0; r < 4; ++r) {
            float s = 0.f, q = 0.f;
            #pragma unroll
            for (int ni = 0; ni < 4; ++ni) {
                float v = acc[mi][ni][r] * inv_pass;
                s += v; q += v * v;
            }
            rs[mi][r] = s; rq[mi][r] = q;
        }
    }
    #pragma unroll
    for (int m = 1; m < 16; m <<= 1) {
        #pragma unroll
        for (int mi = 0; mi < 2; ++mi) {
            #pragma unroll
            for (int r = 0; r < 4; ++r) {
                rs[mi][r] += __shfl_xor(rs[mi][r], m, 64);
                rq[mi][r] += __shfl_xor(rq[mi][r], m, 64);
            }
        }
    }
    if ((lane & 15) == 0) {
        const int gK = lane >> 4;
        #pragma unroll
        for (int mi = 0; mi < 2; ++mi) {
            #pragma unroll
            for (int r = 0; r < 4; ++r) {
                int o = wave * 32 + mi * 16 + gK * 4 + r;
                s1_part[(jt * NB + n) * OUTC + o] = rs[mi][r];
                s2_part[blk * OUTC + o]           = rq[mi][r];
            }
        }
    }
#undef LDA
#undef LDB
#undef WRITEB
#undef COMPUTE
}

// ---- kernel 3 (fused finalize+broadcast): block = (n, 16 channels). ----
__global__ __launch_bounds__(256) void finalize_bcast_kernel(
    const float* __restrict__ s1_part,   // [NJT][NB][OUTC]
    const float* __restrict__ s2_part,   // [256][OUTC]
    const float* __restrict__ gamma,
    const float* __restrict__ beta,
    float* __restrict__ out)             // [NB][OUTC][1024]
{
    const int tid   = threadIdx.x;
    const int slice = tid & 15;
    const int o_l   = tid >> 4;
    const int n0    = blockIdx.x >> 4;
    const int o     = (blockIdx.x & 15) * 16 + o_l;

    float S1 = 0.f, S2 = 0.f;
    #pragma unroll
    for (int q = 0; q < 16; ++q) {
        int p = slice * 16 + q;          // covers all 256 partials
        S1 += s1_part[p * OUTC + o];
        S2 += s2_part[p * OUTC + o];
    }
    float s1n = s1_part[(slice * NB + n0) * OUTC + o];   // jt = slice
    #pragma unroll
    for (int m = 1; m < 16; m <<= 1) {
        S1  += __shfl_xor(S1, m, 64);
        S2  += __shfl_xor(S2, m, 64);
        s1n += __shfl_xor(s1n, m, 64);
    }
    float mean = S1 * (1.f / 16384.f);
    float var  = S2 * (1.f / 16384.f) - mean * mean;   // biased var (matches ref)
    float inv  = rsqrtf(var + 1e-5f);
    float v = gamma[o] * (s1n * (1.f / 1024.f) - mean) * inv + beta[o];

    float4 vv = make_float4(v, v, v, v);
    float4* dst = reinterpret_cast<float4*>(out + ((size_t)(n0 * OUTC + o)) * HW);
    #pragma unroll
    for (int it = 0; it < 16; ++it)
        dst[it * 16 + slice] = vv;
}

extern "C" void kernel_launch(void* const* d_in, const int* in_sizes, int n_in,
                              void* d_out, int out_size, void* d_ws, size_t ws_size,
                              hipStream_t stream) {
    const float* x     = (const float*)d_in[0];
    const float* W     = (const float*)d_in[1];
    const float* gamma = (const float*)d_in[2];
    const float* beta  = (const float*)d_in[3];
    float* out = (float*)d_out;

    char* ws = (char*)d_ws;
    unsigned short* Afrag = (unsigned short*)ws;                 // 1 MiB
    float* s1_part = (float*)(ws + (1 << 20));                   // 256 KB
    float* s2_part = (float*)(ws + (1 << 20) + (256 << 10));     // 256 KB

    hipLaunchKernelGGL(wprep_kernel, dim3(256), dim3(256), 0, stream, W, Afrag);
    hipLaunchKernelGGL(gemm_stats_kernel, dim3(256), dim3(512), 0, stream,
                       x, Afrag, s1_part, s2_part);
    hipLaunchKernelGGL(finalize_bcast_kernel, dim3(NB * (OUTC / 16)), dim3(256), 0, stream,
                       s1_part, s2_part, gamma, beta, out);
}

// Round 10
// 49.773 us; speedup vs baseline: 1.8142x; 1.8142x over previous
//
#include <hip/hip_runtime.h>
#include <hip/hip_bf16.h>
#include <stdint.h>

#define NB   16
#define CIN  2048
#define OUTC 256
#define HW   1024
#define BJ   64
#define BK   64
#define NJT  (HW / BJ)          // 16 j-tiles
#define KSTEPS (CIN / BK)       // 32 steps of 64 k

typedef __attribute__((ext_vector_type(8))) short bf16x8;
typedef __attribute__((ext_vector_type(4))) float f32x4;
typedef __attribute__((ext_vector_type(4))) unsigned int u32x4;

__device__ __forceinline__ unsigned int f2bf(float f) {
    union { float f; unsigned int u; } a; a.f = f;
    return (a.u + 0x7FFFu + ((a.u >> 16) & 1u)) >> 16;  // RNE
}

// Step-end barrier: drain LDS ops (incl. the ds_write), then join.
__device__ __forceinline__ void block_sync_lds() {
    asm volatile("s_waitcnt lgkmcnt(0)" ::: "memory");
    __builtin_amdgcn_s_barrier();
    asm volatile("" ::: "memory");
}
// Phase barrier: scheduling alignment only (no correctness need) — keeps all
// waves issuing ds_read + VMEM + MFMA in every phase so LDS and L1 overlap.
__device__ __forceinline__ void phase_bar() {
    asm volatile("" ::: "memory");
    __builtin_amdgcn_s_barrier();
    asm volatile("" ::: "memory");
}

// ---- kernel 1: W fp32 -> bf16 A-fragments in MFMA lane order. ----
__global__ void wprep_kernel(const float* __restrict__ W, unsigned short* __restrict__ Afrag) {
    int g  = blockIdx.x * blockDim.x + threadIdx.x;   // 65536
    int o  = g >> 8;
    int kc = g & 255;
    const float4* p = reinterpret_cast<const float4*>(W + o * CIN + kc * 8);
    float4 v0 = p[0], v1 = p[1];
    u32x4 pk;
    pk.x = f2bf(v0.x) | (f2bf(v0.y) << 16);
    pk.y = f2bf(v0.z) | (f2bf(v0.w) << 16);
    pk.z = f2bf(v1.x) | (f2bf(v1.y) << 16);
    pk.w = f2bf(v1.z) | (f2bf(v1.w) << 16);
    int ks32 = kc >> 2, g8 = kc & 3;
    int lane = g8 * 16 + (o & 15), ot = o >> 4;
    *reinterpret_cast<u32x4*>(Afrag + (((size_t)ks32 * 16 + ot) * 64 + lane) * 8) = pk;
}

// ---- kernel 2: 4-phase interleaved GEMM ----
__global__ __launch_bounds__(512, 2) void gemm_stats_kernel(
    const float* __restrict__ x,             // [16][2048][1024]
    const unsigned short* __restrict__ Afrag,
    float* __restrict__ s1_part,             // [NJT][NB][OUTC]
    float* __restrict__ s2_part)             // [256][OUTC]
{
    __shared__ __align__(16) unsigned short B0[4096], B1[4096]; // 8 KB each

    const int tid  = threadIdx.x;
    const int lane = tid & 63;
    const int wave = tid >> 6;
    const int blk  = blockIdx.x;   // 0..255
    const int n    = blk >> 4;
    const int jt   = blk & 15;
    const int j0   = jt * BJ;

    const float* xn = x + (size_t)n * CIN * HW;

    const int bj = tid & 63;
    const int kh = tid >> 6;
    const float* Bgp = xn + (size_t)(kh * 8) * HW + j0 + bj;
    const int offB = (kh >> 2) * 2048 + (bj >> 4) * 512 + (kh & 3) * 128 + (bj & 15) * 8;

    const int rbase = lane * 8;    // fragment-linear read base (+ h*2048 + ni*512)
    const unsigned short* Ab = Afrag + (size_t)lane * 8;

#define LDA(ks, R) { _Pragma("unroll") \
    for (int h = 0; h < 2; ++h) _Pragma("unroll") for (int t = 0; t < 2; ++t) \
        R[h * 2 + t] = *(const u32x4*)(Ab + ((((ks) * 2 + h) * 16 + 2 * wave + t) * 64) * 8); }
#define LDB2(ks, F, i0) { int kk = ((ks) < KSTEPS) ? (ks) : KSTEPS - 1; \
    const float* p = Bgp + (size_t)kk * BK * HW; \
    F[i0] = p[(size_t)(i0) * HW]; F[(i0) + 1] = p[(size_t)((i0) + 1) * HW]; }
#define WRITEB(Bb, F) { u32x4 pk; \
    pk.x = f2bf(F[0]) | (f2bf(F[1]) << 16); pk.y = f2bf(F[2]) | (f2bf(F[3]) << 16); \
    pk.z = f2bf(F[4]) | (f2bf(F[5]) << 16); pk.w = f2bf(F[6]) | (f2bf(F[7]) << 16); \
    *(u32x4*)&Bb[offB] = pk; }
#define BFRAG(Bb, h, ni) (*(const bf16x8*)&Bb[(h) * 2048 + (ni) * 512 + rbase])
#define MFMA4(R, hh, blo, bhi, ni0) { \
    bf16x8 a0_ = *(const bf16x8*)&R[(hh) * 2 + 0]; \
    bf16x8 a1_ = *(const bf16x8*)&R[(hh) * 2 + 1]; \
    __builtin_amdgcn_s_setprio(1); \
    acc[0][ni0]     = __builtin_amdgcn_mfma_f32_16x16x32_bf16(a0_, blo, acc[0][ni0], 0, 0, 0); \
    acc[1][ni0]     = __builtin_amdgcn_mfma_f32_16x16x32_bf16(a1_, blo, acc[1][ni0], 0, 0, 0); \
    acc[0][(ni0)+1] = __builtin_amdgcn_mfma_f32_16x16x32_bf16(a0_, bhi, acc[0][(ni0)+1], 0, 0, 0); \
    acc[1][(ni0)+1] = __builtin_amdgcn_mfma_f32_16x16x32_bf16(a1_, bhi, acc[1][(ni0)+1], 0, 0, 0); \
    __builtin_amdgcn_s_setprio(0); }

// One K-step, 4 phases. tv: step index. bufC: compute buffer. bufN: stage target.
// BsW: registers holding step tv+1 data (written at p3). BsL: receives tv+2.
// Acur: A for this step. Aalt: receives A for tv+1 (issued at p0).
#define STEP(tv, bufC, bufN, BsL, BsW, Acur, Aalt) { \
    /* p0 */ \
    bf16x8 b0_ = BFRAG(bufC, 0, 0), b1_ = BFRAG(bufC, 0, 1); \
    LDB2((tv) + 2, BsL, 0); \
    LDA(((tv) + 1 < KSTEPS) ? (tv) + 1 : KSTEPS - 1, Aalt); \
    MFMA4(Acur, 0, b0_, b1_, 0); \
    phase_bar(); \
    /* p1 */ \
    bf16x8 b2_ = BFRAG(bufC, 0, 2), b3_ = BFRAG(bufC, 0, 3); \
    LDB2((tv) + 2, BsL, 2); \
    MFMA4(Acur, 0, b2_, b3_, 2); \
    phase_bar(); \
    /* p2 */ \
    bf16x8 b4_ = BFRAG(bufC, 1, 0), b5_ = BFRAG(bufC, 1, 1); \
    LDB2((tv) + 2, BsL, 4); \
    MFMA4(Acur, 1, b4_, b5_, 0); \
    phase_bar(); \
    /* p3 */ \
    bf16x8 b6_ = BFRAG(bufC, 1, 2), b7_ = BFRAG(bufC, 1, 3); \
    LDB2((tv) + 2, BsL, 6); \
    if ((tv) + 1 < KSTEPS) { WRITEB(bufN, BsW); } \
    MFMA4(Acur, 1, b6_, b7_, 2); \
    if ((tv) + 1 < KSTEPS) { block_sync_lds(); } \
}

    f32x4 acc[2][4] = {};
    u32x4 Aa0[4], Aa1[4];
    float BsA[8], BsB[8];

    // prologue: stage step 0 into B0; load step 1 into BsB; A for step 0.
    LDB2(0, BsA, 0); LDB2(0, BsA, 2); LDB2(0, BsA, 4); LDB2(0, BsA, 6);
    LDA(0, Aa0);
    LDB2(1, BsB, 0); LDB2(1, BsB, 2); LDB2(1, BsB, 4); LDB2(1, BsB, 6);
    WRITEB(B0, BsA);
    block_sync_lds();

    #pragma unroll 1
    for (int ks = 0; ks < KSTEPS; ks += 2) {
        // even step: compute B0/Aa0; stage BsB->B1; load ks+2 -> BsA; A(ks+1)->Aa1
        STEP(ks,     B0, B1, BsA, BsB, Aa0, Aa1);
        // odd step:  compute B1/Aa1; stage BsA->B0; load ks+3 -> BsB; A(ks+2)->Aa0
        STEP(ks + 1, B1, B0, BsB, BsA, Aa1, Aa0);
    }

    // ---- epilogue: per-channel sum / sum-of-squares over this block's 64 j ----
    // C/D layout: col(j) = lane&15, row = (lane>>4)*4 + r  [m89]
    float rs[2][4], rq[2][4];
    #pragma unroll
    for (int mi = 0; mi < 2; ++mi) {
        #pragma unroll
        for (int r = 0; r < 4; ++r) {
            float s = 0.f, q = 0.f;
            #pragma unroll
            for (int ni = 0; ni < 4; ++ni) {
                float v = acc[mi][ni][r];
                s += v; q += v * v;
            }
            rs[mi][r] = s; rq[mi][r] = q;
        }
    }
    #pragma unroll
    for (int m = 1; m < 16; m <<= 1) {
        #pragma unroll
        for (int mi = 0; mi < 2; ++mi) {
            #pragma unroll
            for (int r = 0; r < 4; ++r) {
                rs[mi][r] += __shfl_xor(rs[mi][r], m, 64);
                rq[mi][r] += __shfl_xor(rq[mi][r], m, 64);
            }
        }
    }
    if ((lane & 15) == 0) {
        const int gK = lane >> 4;
        #pragma unroll
        for (int mi = 0; mi < 2; ++mi) {
            #pragma unroll
            for (int r = 0; r < 4; ++r) {
                int o = wave * 32 + mi * 16 + gK * 4 + r;
                s1_part[(jt * NB + n) * OUTC + o] = rs[mi][r];
                s2_part[blk * OUTC + o]           = rq[mi][r];
            }
        }
    }
#undef LDA
#undef LDB2
#undef WRITEB
#undef BFRAG
#undef MFMA4
#undef STEP
}

// ---- kernel 3 (fused finalize+broadcast): block = (n, 16 channels). ----
__global__ __launch_bounds__(256) void finalize_bcast_kernel(
    const float* __restrict__ s1_part,   // [NJT][NB][OUTC]
    const float* __restrict__ s2_part,   // [256][OUTC]
    const float* __restrict__ gamma,
    const float* __restrict__ beta,
    float* __restrict__ out)             // [NB][OUTC][1024]
{
    const int tid   = threadIdx.x;
    const int slice = tid & 15;
    const int o_l   = tid >> 4;
    const int n0    = blockIdx.x >> 4;
    const int o     = (blockIdx.x & 15) * 16 + o_l;

    float S1 = 0.f, S2 = 0.f;
    #pragma unroll
    for (int q = 0; q < 16; ++q) {
        int p = slice * 16 + q;          // covers all 256 partials
        S1 += s1_part[p * OUTC + o];
        S2 += s2_part[p * OUTC + o];
    }
    float s1n = s1_part[(slice * NB + n0) * OUTC + o];   // jt = slice
    #pragma unroll
    for (int m = 1; m < 16; m <<= 1) {
        S1  += __shfl_xor(S1, m, 64);
        S2  += __shfl_xor(S2, m, 64);
        s1n += __shfl_xor(s1n, m, 64);
    }
    float mean = S1 * (1.f / 16384.f);
    float var  = S2 * (1.f / 16384.f) - mean * mean;   // biased var (matches ref)
    float inv  = rsqrtf(var + 1e-5f);
    float v = gamma[o] * (s1n * (1.f / 1024.f) - mean) * inv + beta[o];

    float4 vv = make_float4(v, v, v, v);
    float4* dst = reinterpret_cast<float4*>(out + ((size_t)(n0 * OUTC + o)) * HW);
    #pragma unroll
    for (int it = 0; it < 16; ++it)
        dst[it * 16 + slice] = vv;
}

extern "C" void kernel_launch(void* const* d_in, const int* in_sizes, int n_in,
                              void* d_out, int out_size, void* d_ws, size_t ws_size,
                              hipStream_t stream) {
    const float* x     = (const float*)d_in[0];
    const float* W     = (const float*)d_in[1];
    const float* gamma = (const float*)d_in[2];
    const float* beta  = (const float*)d_in[3];
    float* out = (float*)d_out;

    char* ws = (char*)d_ws;
    unsigned short* Afrag = (unsigned short*)ws;                 // 1 MiB
    float* s1_part = (float*)(ws + (1 << 20));                   // 256 KB
    float* s2_part = (float*)(ws + (1 << 20) + (256 << 10));     // 256 KB

    hipLaunchKernelGGL(wprep_kernel, dim3(256), dim3(256), 0, stream, W, Afrag);
    hipLaunchKernelGGL(gemm_stats_kernel, dim3(256), dim3(512), 0, stream,
                       x, Afrag, s1_part, s2_part);
    hipLaunchKernelGGL(finalize_bcast_kernel, dim3(NB * (OUTC / 16)), dim3(256), 0, stream,
                       s1_part, s2_part, gamma, beta, out);
}